// Round 9
// baseline (544.380 us; speedup 1.0000x reference)
//
#include <hip/hip_runtime.h>
#include <cstdint>

#define NPIX  1024
#define NH    992
#define NEDGE 1984
#define NSORT 2048
#define HFS   4300
#define POOLN (NPIX + 2*HFS)   // 9624 u32 entries per phase

typedef unsigned long long u64;
typedef unsigned int u32;

// root_ pack (labeled live sets only; 0 == dead/unlabeled):
// sL[0,11) | off[11,25) | len[25,36) | cap[36,47)
static __device__ __forceinline__ u64 packRoot(int sL,int off,int len,int cap){
    return (u64)(u32)(sL & 0x7FF) | ((u64)(u32)(off & 0x3FFF) << 11) |
           ((u64)(u32)(len & 0x7FF) << 25) | ((u64)(u32)(cap & 0x7FF) << 36);
}
#define R_SL(R)  ((int)((R) & 0x7FF))
#define R_OFF(R) ((int)(((R)>>11) & 0x3FFF))
#define R_LEN(R) ((int)(((R)>>25) & 0x7FF))
#define R_CAP(R) ((int)(((R)>>36) & 0x7FF))

static __device__ __forceinline__ int rdl(int v, int l){ return __builtin_amdgcn_readlane(v, l); }

static __device__ __forceinline__ u64 sxor64(u64 v, int m){
    u32 lo = (u32)__shfl_xor((int)(v & 0xFFFFFFFFull), m, 64);
    u32 hi = (u32)__shfl_xor((int)(v >> 32), m, 64);
    return ((u64)hi << 32) | lo;
}

// in-register compare-exchange: x at lower global index
#define CE(x, y, up) { u64 _a=(x), _b=(y); bool _lt=(_a<_b); \
    u64 _mn=_lt?_a:_b, _mx=_lt?_b:_a; (x)=(up)?_mn:_mx; (y)=(up)?_mx:_mn; }
// cross-lane compare-exchange via shfl_xor
#define CEX(x, xm, keepmin) { u64 _p=sxor64((x),(xm)); bool _lt=((x)<_p); \
    u64 _mn=_lt?(x):_p, _mx=_lt?_p:(x); (x)=(keepmin)?_mn:_mx; }

static __device__ __forceinline__ int wredi(int v){
    #pragma unroll
    for (int o = 32; o > 0; o >>= 1) v += __shfl_xor(v, o, 64);
    return v;
}
static __device__ __forceinline__ float wredf(float v){
    #pragma unroll
    for (int o = 32; o > 0; o >>= 1) v += __shfl_xor(v, o, 64);
    return v;
}

// interleaved dual find with path-halving (cross-lane races benign: any
// stored value is an ancestor)
static __device__ __forceinline__ void find2(short* par_, int &ra, int &rb){
    for (;;) {
        int pa = par_[ra], pb = par_[rb];
        bool fa = (pa != ra), fb = (pb != rb);
        if (!fa && !fb) break;
        int ga = par_[pa], gb = par_[pb];
        if (fa) { par_[ra] = (short)ga; ra = ga; }
        if (fb) { par_[rb] = (short)gb; rb = gb; }
    }
}

__global__ __launch_bounds__(128) void malis_kernel(
    const float* __restrict__ pred,
    const float* __restrict__ target,
    const float* __restrict__ lr_p,
    const float* __restrict__ lrp_p,
    float* __restrict__ out)
{
    const int tid  = threadIdx.x;
    const int lane = tid & 63;
    const int wv   = tid >> 6;        // wave 0: negative pass, wave 1: positive pass
    const int bid  = blockIdx.x;
    const int bb   = bid >> 6;
    const int win  = bid & 63;
    const int wy   = win >> 3, wx = win & 7;
    const int base = bb * 65536 + (wy * 32) * 256 + wx * 32;

    // ---- LDS (~155.6 KB; 1 block/CU) ----
    __shared__ __align__(16) u32 Ks[2][NSORT]; // 16384 sorted edge indices
    __shared__ u64   root[2][NPIX];         // 16384 (replay only)
    __shared__ float predL[NPIX];           // 4096
    __shared__ float costs[NEDGE];          // 7936
    __shared__ u32   eab[NEDGE];            // 7936  a | b<<16
    __shared__ u32   poolS[2][POOLN];       // 76992 label-count arrays {lab<<16|cnt}
    __shared__ u32   Q[2][NPIX];            // 8192  weighted-merge records {e,ra,rb}
    __shared__ float Qw[2][NPIX];           // 8192  weights (claim array during drain)
    __shared__ short seg[NPIX];             // 2048
    __shared__ short par[2][NPIX];          // 4096
    __shared__ short H[2][NPIX + 1];        // 4100 (slow-path histogram only)
    __shared__ unsigned char tgtL[NPIX];    // 1024
    __shared__ unsigned char gtcL[NEDGE];   // 1984
    __shared__ int   flags[2];

    // early scratch overlaid on poolS (dead until UF init)
    unsigned char* mA    = (unsigned char*)poolS;
    unsigned char* mB    = mA + NPIX;
    short*         labId = (short*)(mA + 2 * NPIX);

    // ---- load window ----
    for (int i = tid; i < NPIX; i += 128) {
        int r = i >> 5, c = i & 31;
        float pv = pred[base + r * 256 + c];
        float tv = target[base + r * 256 + c];
        predL[i] = pv;
        tgtL[i]  = (unsigned char)tv;
        mA[i]    = (tv == 0.0f) ? 1 : 0;
    }
    if (tid == 0) flags[1] = 0;
    __syncthreads();

    // ---- dilate 5x (4-neighborhood) ----
    unsigned char* srcm = mA;
    unsigned char* dstm = mB;
    for (int it = 0; it < 5; ++it) {
        for (int i = tid; i < NPIX; i += 128) {
            int r = i >> 5, c = i & 31;
            unsigned char v = srcm[i];
            if (r > 0)  v |= srcm[i - 32];
            if (r < 31) v |= srcm[i + 32];
            if (c > 0)  v |= srcm[i - 1];
            if (c < 31) v |= srcm[i + 1];
            dstm[i] = v;
        }
        __syncthreads();
        unsigned char* t2 = srcm; srcm = dstm; dstm = t2;
    }

    // ---- CCL (8-conn) on fg = !dilated ----
    for (int i = tid; i < NPIX; i += 128)
        seg[i] = srcm[i] ? (short)-1 : (short)i;
    __syncthreads();

    for (;;) {
        if (tid == 0) flags[0] = 0;
        __syncthreads();
        bool any = false;
        for (int i = tid; i < NPIX; i += 128) {
            int cur = seg[i];
            if (cur < 0) continue;
            int r = i >> 5, c = i & 31;
            int m = cur;
            if (r > 0) {
                if (c > 0)  { int t = seg[i - 33]; if (t >= 0 && t < m) m = t; }
                { int t = seg[i - 32]; if (t >= 0 && t < m) m = t; }
                if (c < 31) { int t = seg[i - 31]; if (t >= 0 && t < m) m = t; }
            }
            if (c > 0)  { int t = seg[i - 1]; if (t >= 0 && t < m) m = t; }
            if (c < 31) { int t = seg[i + 1]; if (t >= 0 && t < m) m = t; }
            if (r < 31) {
                if (c > 0)  { int t = seg[i + 31]; if (t >= 0 && t < m) m = t; }
                { int t = seg[i + 32]; if (t >= 0 && t < m) m = t; }
                if (c < 31) { int t = seg[i + 33]; if (t >= 0 && t < m) m = t; }
            }
            #pragma unroll
            for (int t2 = 0; t2 < 6; ++t2) {
                int s2 = seg[m];
                if (s2 >= 0 && s2 < m) m = s2; else break;
            }
            if (m < cur) { seg[i] = (short)m; any = true; }
        }
        if (any) flags[0] = 1;
        __syncthreads();
        if (flags[0] == 0) break;
        __syncthreads();
    }

    // compact label ids: seg -> 0 (bg) or 1..K
    for (int i = tid; i < NPIX; i += 128)
        if (seg[i] == (short)i) labId[i] = (short)atomicAdd(&flags[1], 1);
    __syncthreads();
    for (int i = tid; i < NPIX; i += 128) {
        short s2 = seg[i];
        seg[i] = (s2 < 0) ? (short)0 : (short)(labId[s2] + 1);
    }

    // ---- edges (reference order: 992 horizontal then 992 vertical) ----
    for (int e = tid; e < NEDGE; e += 128) {
        int a, b2;
        if (e < NH) { int r = e / 31, c = e - r * 31; a = r * 32 + c; b2 = a + 1; }
        else        { int q = e - NH; int r = q >> 5, c = q & 31; a = r * 32 + c; b2 = a + 32; }
        eab[e]   = (u32)a | ((u32)b2 << 16);
        costs[e] = predL[a] + predL[b2];
        gtcL[e]  = (unsigned char)(tgtL[a] + tgtL[b2]);
    }
    __syncthreads();
    // ======== no block barriers below this line: waves fully decoupled ========

    const int ph = wv;                 // 0 = neg, 1 = pos
    u32*   Ks_   = Ks[ph];
    short* par_  = par[ph];
    u64*   root_ = root[ph];
    u32*   pool_ = poolS[ph];
    short* H_    = H[ph];
    u32*   Q_    = Q[ph];
    float* Qw_   = Qw[ph];
    u32*   claim_= (u32*)Qw[ph];       // claim array during drain (Qw dead until replay)

    // ---- register-resident bitonic sort of 2048 u64 keys ----
    // layout: global index i = lane*32 + r; key = (~bits(cost))<<32 | e
    // ascending sort == (cost desc, idx asc) == exact reference order
    u64 sk[32];
    #pragma unroll
    for (int r = 0; r < 32; ++r) {
        int e = lane * 32 + r;
        u64 kv = ~0ULL;                       // padding sorts to tail, never read
        if (e < NEDGE) {
            float cv = costs[e];
            int g = gtcL[e];
            if (ph == 0) { if (g > 20) cv = 20.0f; }
            else         { if (g < 10) cv = 0.0f; }
            kv = (((u64)(~__float_as_uint(cv))) << 32) | (u32)e;  // costs >= 0: monotone bits
        }
        sk[r] = kv;
    }
    #pragma unroll
    for (int kk2 = 2; kk2 <= 32; kk2 <<= 1) {
        #pragma unroll
        for (int j = kk2 >> 1; j > 0; j >>= 1) {
            #pragma unroll
            for (int r = 0; r < 32; ++r) {
                if ((r & j) == 0) {
                    bool up = (kk2 == 32) ? ((lane & 1) == 0) : ((r & kk2) == 0);
                    CE(sk[r], sk[r | j], up);
                }
            }
        }
    }
    #pragma unroll
    for (int kk2 = 64; kk2 <= 2048; kk2 <<= 1) {
        const bool up = ((lane & (kk2 >> 5)) == 0);
        #pragma unroll
        for (int j = kk2 >> 1; j >= 32; j >>= 1) {
            const int xm = j >> 5;
            const bool keepmin = (((lane & xm) == 0) == up);
            #pragma unroll
            for (int r = 0; r < 32; ++r) { CEX(sk[r], xm, keepmin); }
        }
        #pragma unroll
        for (int j = 16; j > 0; j >>= 1) {
            #pragma unroll
            for (int r = 0; r < 32; ++r) {
                if ((r & j) == 0) { CE(sk[r], sk[r | j], up); }
            }
        }
    }
    #pragma unroll
    for (int r = 0; r < 32; r += 4) {
        uint4 v4;
        v4.x = (u32)sk[r]; v4.y = (u32)sk[r+1]; v4.z = (u32)sk[r+2]; v4.w = (u32)sk[r+3];
        *(uint4*)&Ks_[lane * 32 + r] = v4;
    }

    // ---- union-find init; labeled pixel i owns pool slot i = {seg[i], cnt 1} ----
    // Invariant (labeled-wins unions): comp labeled <=> seg[root] != 0; labeled
    // sets change only at weighted merges (deferred to replay).
    for (int i = lane; i < NPIX; i += 64) {
        par_[i] = (short)i;
        short s2 = seg[i];
        if (s2) {
            root_[i] = packRoot(1, i, 1, 1);
            pool_[i] = ((u32)(unsigned short)s2 << 16) | 1u;
        } else {
            root_[i] = 0;                     // 0 == not a live labeled set
        }
        H_[i] = 0;
        claim_[i] = 0;                        // tags start at round 1 > 0
    }
    if (lane == 0) H_[NPIX] = 0;
    __builtin_amdgcn_wave_barrier();

    // ---- Kruskal drain: single global claim loop, rank-priority ----
    // Lane L owns ranks {L, L+64, ..., L+1920}. Per round each lane proposes
    // its lowest unresolved edge; claims its loser (weighted: both roots) via
    // round-tagged atomicMax (tag = round<<11 | (2047-rank): higher round beats
    // stale claims => no reset stage; within a round lower rank wins).
    // Exactness: merge set is order-independent for a fixed total order;
    // same-loser conflicts excluded by claims; orientation goes strictly
    // uphill in (labeled, -index) potential => par_ stays acyclic; plumbing/
    // mixed merges never change labeled multisets; weighted pairs sharing a
    // root serialize in rank order via claims => recorded root pairs + Q order
    // reproduce serial weights exactly.
    int qn = 0;
    const u64 ltm = (1ull << lane) - 1;
    {
        int i = 0;
        bool loaded = false;
        int myE = 0, ra = 0, rb = 0;
        for (u32 round = 1;; ++round) {
            if (i < 31) {
                if (!loaded) {
                    myE = (int)Ks_[i * 64 + lane];
                    u32 ab = eab[myE];
                    ra = (int)(ab & 0xFFFF); rb = (int)(ab >> 16);
                    loaded = true;
                }
                find2(par_, ra, rb);
                while (ra == rb) {                 // dead forever: skip
                    ++i;
                    if (i >= 31) { loaded = false; break; }
                    myE = (int)Ks_[i * 64 + lane];
                    u32 ab = eab[myE];
                    ra = (int)(ab & 0xFFFF); rb = (int)(ab >> 16);
                    find2(par_, ra, rb);
                }
            }
            bool have = (i < 31);
            if (!__ballot(have)) break;

            bool lA = false, lB = false;
            if (have) { lA = (seg[ra] != 0); lB = (seg[rb] != 0); }
            int mn = ra < rb ? ra : rb;
            int mx = ra < rb ? rb : ra;
            int winner = (lA == lB) ? mn : (lA ? ra : rb);
            int loser  = (lA == lB) ? mx : (lA ? rb : ra);
            bool wgt = lA && lB;
            u32 tag = (round << 11) | (2047u - (u32)(i * 64 + lane));
            if (have) {
                atomicMax(&claim_[loser], tag);
                if (wgt) atomicMax(&claim_[winner], tag);
            }
            bool sel = false;
            if (have) {
                u32 c1 = claim_[loser];
                u32 c2 = wgt ? claim_[winner] : tag;
                sel = (c1 == tag) && (c2 == tag);
            }
            u64 wm = __ballot(sel && wgt);
            if (sel && wgt)
                Q_[qn + __popcll(wm & ltm)] = (u32)myE | ((u32)mn << 11) | ((u32)mx << 21);
            qn += (int)__popcll(wm);
            if (sel) {
                par_[loser] = (short)winner;
                ++i; loaded = false;               // resolved; advance next round
            }
        }
    }
    __builtin_amdgcn_wave_barrier();

    // ---- replay: ~89 weighted merges in recorded order (exact roots) ----
    u32 bump = NPIX;
    u32 halfEnd = NPIX + HFS;
    int curHalf = 0;

    auto do_gc = [&]() {           // ping-pong compaction; live entries <= 1024 < HFS
        u32 tgt = (curHalf == 0) ? (u32)(NPIX + HFS) : (u32)NPIX;
        u32 nb = tgt;
        for (int c = 0; c < 16; ++c) {
            int i0 = c * 64 + lane;
            bool live = (root_[i0] != 0);
            u64 rbm = __ballot(live);
            while (rbm) {
                int j = __ffsll(rbm) - 1; rbm &= rbm - 1;
                int r = c * 64 + j;
                u64 R = root_[r];
                int len = R_LEN(R);
                int off = R_OFF(R);
                for (int t = lane; t < len; t += 64) {
                    u32 v2 = pool_[off + t];
                    pool_[nb + t] = v2;
                }
                __builtin_amdgcn_wave_barrier();
                if (lane == 0) root_[r] = packRoot(R_SL(R), (int)nb, len, len);
                nb += (u32)len;
            }
        }
        bump = nb;
        halfEnd = tgt + HFS;
        curHalf ^= 1;
    };

    int lastW = -1; u64 lastPack = 0;   // register forwarding across chained merges
    for (int q = 0; q < qn; ++q) {
        u32 rec = Q_[q];
        int A  = (int)((rec >> 11) & 0x3FF);   // A = min => winner
        int B  = (int)((rec >> 21) & 0x3FF);
        u64 RA = (A == lastW) ? lastPack : root_[A];
        u64 RB = (B == lastW) ? lastPack : root_[B];
        int sLa = R_SL(RA), sLb = R_SL(RB);
        int lenA = R_LEN(RA), lenB = R_LEN(RB);
        if (bump + (u32)(lenA + lenB + 8) > halfEnd) {
            do_gc();
            lastW = -1;
            RA = root_[A]; RB = root_[B];
            lenA = R_LEN(RA); lenB = R_LEN(RB);
        }
        int offA = R_OFF(RA), capA = R_CAP(RA);
        int offB = R_OFF(RB), capB = R_CAP(RB);
        int offS, lenS, offL, lenL, capL;
        if (lenA <= lenB) { offS = offA; lenS = lenA; offL = offB; lenL = lenB; capL = capB; }
        else              { offS = offB; lenS = lenB; offL = offA; lenL = lenA; capL = capA; }
        int same = 0, dOff, dLen, dCap;

        if (lenS + lenL <= 64) {
            // register path: lists live in lanes; match via readlane+ballot
            u32 eL = (lane < lenL) ? pool_[offL + lane] : 0u;
            u32 eS = (lane < lenS) ? pool_[offS + lane] : 0u;
            dLen = lenL;
            for (int t = 0; t < lenS; ++t) {
                u32 xs = (u32)rdl((int)eS, t);
                bool match = (lane < lenL) && ((eL >> 16) == (xs >> 16));
                u64 mb = __ballot(match);
                if (mb) {                               // uniform branch
                    int ml = __ffsll(mb) - 1;
                    same += (int)(xs & 0xFFFF) * ((int)rdl((int)eL, ml) & 0xFFFF);
                    if (match) eL += (xs & 0xFFFF);
                } else {
                    if (lane == dLen) eL = xs;          // append to free lane
                    dLen++;
                }
            }
            if (dLen <= capL) { dOff = offL; dCap = capL; }     // in place
            else { dOff = (int)bump; dCap = (dLen + 3) & ~3; bump += (u32)dCap; }
            if (lane < dLen) pool_[dOff + lane] = eL;
        } else {
            // slow generic: stride loops + LDS histogram, always-alloc upper bound
            dOff = (int)bump;
            dCap = (lenL + lenS + 4) & ~3; bump += (u32)dCap;
            for (int j = lane; j < lenS; j += 64) {
                u32 es = pool_[offS + j];
                H_[es >> 16] = (short)(es & 0xFFFF);
            }
            __builtin_amdgcn_wave_barrier();
            int sp = 0;
            for (int j = lane; j < lenL; j += 64) {
                u32 el = pool_[offL + j];
                int h = (int)H_[el >> 16];
                sp += h * (int)(el & 0xFFFF);
                pool_[dOff + j] = el + (u32)h;
                if (h) H_[el >> 16] = 0;
            }
            same = wredi(sp);
            __builtin_amdgcn_wave_barrier();
            int baseU = 0;
            for (int j0 = 0; j0 < lenS; j0 += 64) {
                int j = j0 + lane;
                bool un = false; u32 es = 0;
                if (j < lenS) { es = pool_[offS + j]; un = (H_[es >> 16] != 0); }
                u64 ub = __ballot(un);
                if (un) {
                    int pos = __popcll(ub & ltm);
                    pool_[dOff + lenL + baseU + pos] = es;
                    H_[es >> 16] = 0;
                }
                baseU += __popcll(ub);
            }
            dLen = lenL + baseU;
        }
        u64 newPack = packRoot(sLa + sLb, dOff, dLen, dCap);  // uniform in all lanes
        if (lane == 0) {
            Qw_[q] = (float)(ph ? same : (sLa * sLb - same));
            root_[A] = newPack;
            root_[B] = 0;
        }
        lastW = A; lastPack = newPack;
        __builtin_amdgcn_wave_barrier();
    }

    // ---- epilogue per wave: sums over the qn recorded (merge) edges only ----
    float s_loc = 0.0f;
    for (int q = lane; q < qn; q += 64) s_loc += Qw_[q];
    const float sn = wredf(s_loc);

    const float scale = ph ? lrp_p[0] : lr_p[0];
    float acc = 0.0f;
    for (int q = lane; q < qn; q += 64) {
        float wv2 = Qw_[q];
        if (wv2 == 0.0f) continue;
        if (sn > 0.0f) wv2 /= sn;
        int me = (int)(Q_[q] & 0x7FF);
        int g = gtcL[me];
        bool zero = ph ? (g < 20) : (g >= 10);
        if (zero) continue;
        u32 ab = eab[me];
        float pa = predL[ab & 0xFFFF], pb = predL[ab >> 16];
        float fa2, fb2;
        if (ph == 0) { fa2 = pa * pa; fb2 = pb * pb; }
        else { float qa = 20.0f - pa, qb = 20.0f - pb; fa2 = qa * qa; fb2 = qb * qb; }
        acc += scale * wv2 * (fa2 + fb2);
    }
    acc = wredf(acc);
    if (lane == 0) atomicAdd(out, acc);
}

__global__ void zero_out_kernel(float* o)
{
    if (threadIdx.x == 0 && blockIdx.x == 0) o[0] = 0.0f;
}

extern "C" void kernel_launch(void* const* d_in, const int* in_sizes, int n_in,
                              void* d_out, int out_size, void* d_ws, size_t ws_size,
                              hipStream_t stream)
{
    const float* pred   = (const float*)d_in[0];
    const float* target = (const float*)d_in[1];
    const float* lr     = (const float*)d_in[2];
    const float* lrp    = (const float*)d_in[3];
    float* out = (float*)d_out;

    zero_out_kernel<<<1, 64, 0, stream>>>(out);
    malis_kernel<<<128, 128, 0, stream>>>(pred, target, lr, lrp, out);
}

// Round 10
// 522.337 us; speedup vs baseline: 1.0422x; 1.0422x over previous
//
#include <hip/hip_runtime.h>
#include <cstdint>

#define NPIX  1024
#define NH    992
#define NEDGE 1984
#define NSORT 2048
#define NGRP  31
#define HFS   4300
#define POOLN (NPIX + 2*HFS)   // 9624 u32 entries per phase

typedef unsigned long long u64;
typedef unsigned int u32;

// root_ pack (labeled live sets only; 0 == dead/unlabeled):
// sL[0,11) | off[11,25) | len[25,36) | cap[36,47)
static __device__ __forceinline__ u64 packRoot(int sL,int off,int len,int cap){
    return (u64)(u32)(sL & 0x7FF) | ((u64)(u32)(off & 0x3FFF) << 11) |
           ((u64)(u32)(len & 0x7FF) << 25) | ((u64)(u32)(cap & 0x7FF) << 36);
}
#define R_SL(R)  ((int)((R) & 0x7FF))
#define R_OFF(R) ((int)(((R)>>11) & 0x3FFF))
#define R_LEN(R) ((int)(((R)>>25) & 0x7FF))
#define R_CAP(R) ((int)(((R)>>36) & 0x7FF))

static __device__ __forceinline__ int rdl(int v, int l){ return __builtin_amdgcn_readlane(v, l); }

static __device__ __forceinline__ u64 sxor64(u64 v, int m){
    u32 lo = (u32)__shfl_xor((int)(v & 0xFFFFFFFFull), m, 64);
    u32 hi = (u32)__shfl_xor((int)(v >> 32), m, 64);
    return ((u64)hi << 32) | lo;
}

// in-register compare-exchange: x at lower global index
#define CE(x, y, up) { u64 _a=(x), _b=(y); bool _lt=(_a<_b); \
    u64 _mn=_lt?_a:_b, _mx=_lt?_b:_a; (x)=(up)?_mn:_mx; (y)=(up)?_mx:_mn; }
// cross-lane compare-exchange via shfl_xor
#define CEX(x, xm, keepmin) { u64 _p=sxor64((x),(xm)); bool _lt=((x)<_p); \
    u64 _mn=_lt?(x):_p, _mx=_lt?_p:(x); (x)=(keepmin)?_mn:_mx; }

static __device__ __forceinline__ int wredi(int v){
    #pragma unroll
    for (int o = 32; o > 0; o >>= 1) v += __shfl_xor(v, o, 64);
    return v;
}
static __device__ __forceinline__ float wredf(float v){
    #pragma unroll
    for (int o = 32; o > 0; o >>= 1) v += __shfl_xor(v, o, 64);
    return v;
}

// interleaved dual find with path-halving (cross-lane races benign: any
// stored value is an ancestor)
static __device__ __forceinline__ void find2(short* par_, int &ra, int &rb){
    for (;;) {
        int pa = par_[ra], pb = par_[rb];
        bool fa = (pa != ra), fb = (pb != rb);
        if (!fa && !fb) break;
        int ga = par_[pa], gb = par_[pb];
        if (fa) { par_[ra] = (short)ga; ra = ga; }
        if (fb) { par_[rb] = (short)gb; rb = gb; }
    }
}

__global__ __launch_bounds__(128) void malis_kernel(
    const float* __restrict__ pred,
    const float* __restrict__ target,
    const float* __restrict__ lr_p,
    const float* __restrict__ lrp_p,
    float* __restrict__ out)
{
    const int tid  = threadIdx.x;
    const int lane = tid & 63;
    const int wv   = tid >> 6;        // wave 0: negative pass, wave 1: positive pass
    const int bid  = blockIdx.x;
    const int bb   = bid >> 6;
    const int win  = bid & 63;
    const int wy   = win >> 3, wx = win & 7;
    const int base = bb * 65536 + (wy * 32) * 256 + wx * 32;

    // ---- LDS (~155.6 KB; 1 block/CU) ----
    __shared__ __align__(16) u32 Ks[2][NSORT]; // 16384 sorted edge indices
    __shared__ u64   root[2][NPIX];         // 16384 (replay only)
    __shared__ float predL[NPIX];           // 4096
    __shared__ float costs[NEDGE];          // 7936
    __shared__ u32   eab[NEDGE];            // 7936  a | b<<16
    __shared__ u32   poolS[2][POOLN];       // 76992 label-count arrays {lab<<16|cnt}
    __shared__ u32   Q[2][NPIX];            // 8192  weighted-merge records {e,ra,rb}
    __shared__ float Qw[2][NPIX];           // 8192  weights (claim array during drain)
    __shared__ short seg[NPIX];             // 2048
    __shared__ short par[2][NPIX];          // 4096
    __shared__ short H[2][NPIX + 1];        // 4100 (slow-path histogram only)
    __shared__ unsigned char tgtL[NPIX];    // 1024
    __shared__ unsigned char gtcL[NEDGE];   // 1984
    __shared__ int   flags[2];

    // early scratch overlaid on poolS (dead until UF init)
    unsigned char* mA    = (unsigned char*)poolS;
    unsigned char* mB    = mA + NPIX;
    short*         labId = (short*)(mA + 2 * NPIX);

    // ---- load window ----
    for (int i = tid; i < NPIX; i += 128) {
        int r = i >> 5, c = i & 31;
        float pv = pred[base + r * 256 + c];
        float tv = target[base + r * 256 + c];
        predL[i] = pv;
        tgtL[i]  = (unsigned char)tv;
        mA[i]    = (tv == 0.0f) ? 1 : 0;
    }
    if (tid == 0) flags[1] = 0;
    __syncthreads();

    // ---- dilate 5x (4-neighborhood) ----
    unsigned char* srcm = mA;
    unsigned char* dstm = mB;
    for (int it = 0; it < 5; ++it) {
        for (int i = tid; i < NPIX; i += 128) {
            int r = i >> 5, c = i & 31;
            unsigned char v = srcm[i];
            if (r > 0)  v |= srcm[i - 32];
            if (r < 31) v |= srcm[i + 32];
            if (c > 0)  v |= srcm[i - 1];
            if (c < 31) v |= srcm[i + 1];
            dstm[i] = v;
        }
        __syncthreads();
        unsigned char* t2 = srcm; srcm = dstm; dstm = t2;
    }

    // ---- CCL (8-conn) on fg = !dilated ----
    for (int i = tid; i < NPIX; i += 128)
        seg[i] = srcm[i] ? (short)-1 : (short)i;
    __syncthreads();

    for (;;) {
        if (tid == 0) flags[0] = 0;
        __syncthreads();
        bool any = false;
        for (int i = tid; i < NPIX; i += 128) {
            int cur = seg[i];
            if (cur < 0) continue;
            int r = i >> 5, c = i & 31;
            int m = cur;
            if (r > 0) {
                if (c > 0)  { int t = seg[i - 33]; if (t >= 0 && t < m) m = t; }
                { int t = seg[i - 32]; if (t >= 0 && t < m) m = t; }
                if (c < 31) { int t = seg[i - 31]; if (t >= 0 && t < m) m = t; }
            }
            if (c > 0)  { int t = seg[i - 1]; if (t >= 0 && t < m) m = t; }
            if (c < 31) { int t = seg[i + 1]; if (t >= 0 && t < m) m = t; }
            if (r < 31) {
                if (c > 0)  { int t = seg[i + 31]; if (t >= 0 && t < m) m = t; }
                { int t = seg[i + 32]; if (t >= 0 && t < m) m = t; }
                if (c < 31) { int t = seg[i + 33]; if (t >= 0 && t < m) m = t; }
            }
            #pragma unroll
            for (int t2 = 0; t2 < 6; ++t2) {
                int s2 = seg[m];
                if (s2 >= 0 && s2 < m) m = s2; else break;
            }
            if (m < cur) { seg[i] = (short)m; any = true; }
        }
        if (any) flags[0] = 1;
        __syncthreads();
        if (flags[0] == 0) break;
        __syncthreads();
    }

    // compact label ids: seg -> 0 (bg) or 1..K
    for (int i = tid; i < NPIX; i += 128)
        if (seg[i] == (short)i) labId[i] = (short)atomicAdd(&flags[1], 1);
    __syncthreads();
    for (int i = tid; i < NPIX; i += 128) {
        short s2 = seg[i];
        seg[i] = (s2 < 0) ? (short)0 : (short)(labId[s2] + 1);
    }

    // ---- edges (reference order: 992 horizontal then 992 vertical) ----
    for (int e = tid; e < NEDGE; e += 128) {
        int a, b2;
        if (e < NH) { int r = e / 31, c = e - r * 31; a = r * 32 + c; b2 = a + 1; }
        else        { int q = e - NH; int r = q >> 5, c = q & 31; a = r * 32 + c; b2 = a + 32; }
        eab[e]   = (u32)a | ((u32)b2 << 16);
        costs[e] = predL[a] + predL[b2];
        gtcL[e]  = (unsigned char)(tgtL[a] + tgtL[b2]);
    }
    __syncthreads();
    // ======== no block barriers below this line: waves fully decoupled ========

    const int ph = wv;                 // 0 = neg, 1 = pos
    u32*   Ks_   = Ks[ph];
    short* par_  = par[ph];
    u64*   root_ = root[ph];
    u32*   pool_ = poolS[ph];
    short* H_    = H[ph];
    u32*   Q_    = Q[ph];
    float* Qw_   = Qw[ph];
    u32*   claim_= (u32*)Qw[ph];       // claim array during drain (Qw dead until replay)

    // ---- register-resident bitonic sort of 2048 u64 keys ----
    // layout: global index i = lane*32 + r; key = (~bits(cost))<<32 | e
    // ascending sort == (cost desc, idx asc) == exact reference order
    u64 sk[32];
    #pragma unroll
    for (int r = 0; r < 32; ++r) {
        int e = lane * 32 + r;
        u64 kv = ~0ULL;                       // padding sorts to tail, never read
        if (e < NEDGE) {
            float cv = costs[e];
            int g = gtcL[e];
            if (ph == 0) { if (g > 20) cv = 20.0f; }
            else         { if (g < 10) cv = 0.0f; }
            kv = (((u64)(~__float_as_uint(cv))) << 32) | (u32)e;  // costs >= 0: monotone bits
        }
        sk[r] = kv;
    }
    #pragma unroll
    for (int kk2 = 2; kk2 <= 32; kk2 <<= 1) {
        #pragma unroll
        for (int j = kk2 >> 1; j > 0; j >>= 1) {
            #pragma unroll
            for (int r = 0; r < 32; ++r) {
                if ((r & j) == 0) {
                    bool up = (kk2 == 32) ? ((lane & 1) == 0) : ((r & kk2) == 0);
                    CE(sk[r], sk[r | j], up);
                }
            }
        }
    }
    #pragma unroll
    for (int kk2 = 64; kk2 <= 2048; kk2 <<= 1) {
        const bool up = ((lane & (kk2 >> 5)) == 0);
        #pragma unroll
        for (int j = kk2 >> 1; j >= 32; j >>= 1) {
            const int xm = j >> 5;
            const bool keepmin = (((lane & xm) == 0) == up);
            #pragma unroll
            for (int r = 0; r < 32; ++r) { CEX(sk[r], xm, keepmin); }
        }
        #pragma unroll
        for (int j = 16; j > 0; j >>= 1) {
            #pragma unroll
            for (int r = 0; r < 32; ++r) {
                if ((r & j) == 0) { CE(sk[r], sk[r | j], up); }
            }
        }
    }
    #pragma unroll
    for (int r = 0; r < 32; r += 4) {
        uint4 v4;
        v4.x = (u32)sk[r]; v4.y = (u32)sk[r+1]; v4.z = (u32)sk[r+2]; v4.w = (u32)sk[r+3];
        *(uint4*)&Ks_[lane * 32 + r] = v4;
    }

    // ---- union-find init; labeled pixel i owns pool slot i = {seg[i], cnt 1} ----
    // Invariant (labeled-wins unions): comp labeled <=> seg[root] != 0; labeled
    // sets change only at weighted merges (deferred to replay).
    for (int i = lane; i < NPIX; i += 64) {
        par_[i] = (short)i;
        short s2 = seg[i];
        if (s2) {
            root_[i] = packRoot(1, i, 1, 1);
            pool_[i] = ((u32)(unsigned short)s2 << 16) | 1u;
        } else {
            root_[i] = 0;                     // 0 == not a live labeled set
        }
        H_[i] = 0;
        claim_[i] = 0;                        // tags start at round 1
    }
    if (lane == 0) H_[NPIX] = 0;
    __builtin_amdgcn_wave_barrier();

    // ---- Kruskal drain: group-ordered, both-root claims = sound local-min ----
    // Groups of 64 in sorted order; a group completes before the next starts,
    // so every alive edge below any proposed rank is itself proposed. Per
    // round, each alive edge claims BOTH roots (round-tagged atomicMax; lower
    // lane = lower rank wins; higher round overrides stale tags — no reset).
    // Selected iff it wins both roots => it is the min-rank alive edge
    // incident to both its components (cut property => selected edges are
    // exactly serial-Kruskal merges with serial comps => exact weights).
    // Selected edges are root-disjoint => parallel par_ writes are safe.
    int qn = 0;
    u32 roundv = 1;
    const u64 ltm = (1ull << lane) - 1;
    for (int g2 = 0; g2 < NGRP; ++g2) {
        int myE = (int)Ks_[g2 * 64 + lane];
        u32 ab = eab[myE];
        int ra = (int)(ab & 0xFFFF);
        int rb = (int)(ab >> 16);
        find2(par_, ra, rb);
        bool alive = (ra != rb);

        for (;;) {
            if (!__ballot(alive)) break;
            u32 tag = (roundv << 6) | (63u - (u32)lane);
            roundv++;
            if (alive) {
                atomicMax(&claim_[ra], tag);
                atomicMax(&claim_[rb], tag);
            }
            bool sel = false;
            if (alive) sel = (claim_[ra] == tag) && (claim_[rb] == tag);

            bool lA = alive && (seg[ra] != 0);
            bool lB = alive && (seg[rb] != 0);
            int mn = ra < rb ? ra : rb;
            int mx = ra < rb ? rb : ra;
            int winner = (lA == lB) ? mn : (lA ? ra : rb);
            int loser  = (lA == lB) ? mx : (lA ? rb : ra);
            bool wgt = lA && lB;

            u64 wm = __ballot(sel && wgt);
            if (sel && wgt)
                Q_[qn + __popcll(wm & ltm)] = (u32)myE | ((u32)mn << 11) | ((u32)mx << 21);
            qn += (int)__popcll(wm);
            if (sel) par_[loser] = (short)winner;     // root-disjoint: parallel-safe
            if (alive) {
                find2(par_, ra, rb);                  // after all merges (in-order LDS)
                alive = (ra != rb);
            }
        }
    }
    __builtin_amdgcn_wave_barrier();

    // ---- replay: ~89 weighted merges in recorded order (exact roots) ----
    u32 bump = NPIX;
    u32 halfEnd = NPIX + HFS;
    int curHalf = 0;

    auto do_gc = [&]() {           // ping-pong compaction; live entries <= 1024 < HFS
        u32 tgt = (curHalf == 0) ? (u32)(NPIX + HFS) : (u32)NPIX;
        u32 nb = tgt;
        for (int c = 0; c < 16; ++c) {
            int i0 = c * 64 + lane;
            bool live = (root_[i0] != 0);
            u64 rbm = __ballot(live);
            while (rbm) {
                int j = __ffsll(rbm) - 1; rbm &= rbm - 1;
                int r = c * 64 + j;
                u64 R = root_[r];
                int len = R_LEN(R);
                int off = R_OFF(R);
                for (int t = lane; t < len; t += 64) {
                    u32 v2 = pool_[off + t];
                    pool_[nb + t] = v2;
                }
                __builtin_amdgcn_wave_barrier();
                if (lane == 0) root_[r] = packRoot(R_SL(R), (int)nb, len, len);
                nb += (u32)len;
            }
        }
        bump = nb;
        halfEnd = tgt + HFS;
        curHalf ^= 1;
    };

    int lastW = -1; u64 lastPack = 0;   // register forwarding across chained merges
    for (int q = 0; q < qn; ++q) {
        u32 rec = Q_[q];
        int A  = (int)((rec >> 11) & 0x3FF);   // A = min => winner
        int B  = (int)((rec >> 21) & 0x3FF);
        u64 RA = (A == lastW) ? lastPack : root_[A];
        u64 RB = (B == lastW) ? lastPack : root_[B];
        int sLa = R_SL(RA), sLb = R_SL(RB);
        int lenA = R_LEN(RA), lenB = R_LEN(RB);
        if (bump + (u32)(lenA + lenB + 8) > halfEnd) {
            do_gc();
            lastW = -1;
            RA = root_[A]; RB = root_[B];
            lenA = R_LEN(RA); lenB = R_LEN(RB);
        }
        int offA = R_OFF(RA), capA = R_CAP(RA);
        int offB = R_OFF(RB), capB = R_CAP(RB);
        int offS, lenS, offL, lenL, capL;
        if (lenA <= lenB) { offS = offA; lenS = lenA; offL = offB; lenL = lenB; capL = capB; }
        else              { offS = offB; lenS = lenB; offL = offA; lenL = lenA; capL = capA; }
        int same = 0, dOff, dLen, dCap;

        if (lenS + lenL <= 64) {
            // register path: lists live in lanes; match via readlane+ballot
            u32 eL = (lane < lenL) ? pool_[offL + lane] : 0u;
            u32 eS = (lane < lenS) ? pool_[offS + lane] : 0u;
            dLen = lenL;
            for (int t = 0; t < lenS; ++t) {
                u32 xs = (u32)rdl((int)eS, t);
                bool match = (lane < lenL) && ((eL >> 16) == (xs >> 16));
                u64 mb = __ballot(match);
                if (mb) {                               // uniform branch
                    int ml = __ffsll(mb) - 1;
                    same += (int)(xs & 0xFFFF) * ((int)rdl((int)eL, ml) & 0xFFFF);
                    if (match) eL += (xs & 0xFFFF);
                } else {
                    if (lane == dLen) eL = xs;          // append to free lane
                    dLen++;
                }
            }
            if (dLen <= capL) { dOff = offL; dCap = capL; }     // in place
            else { dOff = (int)bump; dCap = (dLen + 3) & ~3; bump += (u32)dCap; }
            if (lane < dLen) pool_[dOff + lane] = eL;
        } else {
            // slow generic: stride loops + LDS histogram, always-alloc upper bound
            dOff = (int)bump;
            dCap = (lenL + lenS + 4) & ~3; bump += (u32)dCap;
            for (int j = lane; j < lenS; j += 64) {
                u32 es = pool_[offS + j];
                H_[es >> 16] = (short)(es & 0xFFFF);
            }
            __builtin_amdgcn_wave_barrier();
            int sp = 0;
            for (int j = lane; j < lenL; j += 64) {
                u32 el = pool_[offL + j];
                int h = (int)H_[el >> 16];
                sp += h * (int)(el & 0xFFFF);
                pool_[dOff + j] = el + (u32)h;
                if (h) H_[el >> 16] = 0;
            }
            same = wredi(sp);
            __builtin_amdgcn_wave_barrier();
            int baseU = 0;
            for (int j0 = 0; j0 < lenS; j0 += 64) {
                int j = j0 + lane;
                bool un = false; u32 es = 0;
                if (j < lenS) { es = pool_[offS + j]; un = (H_[es >> 16] != 0); }
                u64 ub = __ballot(un);
                if (un) {
                    int pos = __popcll(ub & ltm);
                    pool_[dOff + lenL + baseU + pos] = es;
                    H_[es >> 16] = 0;
                }
                baseU += __popcll(ub);
            }
            dLen = lenL + baseU;
        }
        u64 newPack = packRoot(sLa + sLb, dOff, dLen, dCap);  // uniform in all lanes
        if (lane == 0) {
            Qw_[q] = (float)(ph ? same : (sLa * sLb - same));
            root_[A] = newPack;
            root_[B] = 0;
        }
        lastW = A; lastPack = newPack;
        __builtin_amdgcn_wave_barrier();
    }

    // ---- epilogue per wave: sums over the qn recorded (merge) edges only ----
    float s_loc = 0.0f;
    for (int q = lane; q < qn; q += 64) s_loc += Qw_[q];
    const float sn = wredf(s_loc);

    const float scale = ph ? lrp_p[0] : lr_p[0];
    float acc = 0.0f;
    for (int q = lane; q < qn; q += 64) {
        float wv2 = Qw_[q];
        if (wv2 == 0.0f) continue;
        if (sn > 0.0f) wv2 /= sn;
        int me = (int)(Q_[q] & 0x7FF);
        int g = gtcL[me];
        bool zero = ph ? (g < 20) : (g >= 10);
        if (zero) continue;
        u32 ab = eab[me];
        float pa = predL[ab & 0xFFFF], pb = predL[ab >> 16];
        float fa2, fb2;
        if (ph == 0) { fa2 = pa * pa; fb2 = pb * pb; }
        else { float qa = 20.0f - pa, qb = 20.0f - pb; fa2 = qa * qa; fb2 = qb * qb; }
        acc += scale * wv2 * (fa2 + fb2);
    }
    acc = wredf(acc);
    if (lane == 0) atomicAdd(out, acc);
}

__global__ void zero_out_kernel(float* o)
{
    if (threadIdx.x == 0 && blockIdx.x == 0) o[0] = 0.0f;
}

extern "C" void kernel_launch(void* const* d_in, const int* in_sizes, int n_in,
                              void* d_out, int out_size, void* d_ws, size_t ws_size,
                              hipStream_t stream)
{
    const float* pred   = (const float*)d_in[0];
    const float* target = (const float*)d_in[1];
    const float* lr     = (const float*)d_in[2];
    const float* lrp    = (const float*)d_in[3];
    float* out = (float*)d_out;

    zero_out_kernel<<<1, 64, 0, stream>>>(out);
    malis_kernel<<<128, 128, 0, stream>>>(pred, target, lr, lrp, out);
}